// Round 7
// baseline (89.115 us; speedup 1.0000x reference)
//
#include <hip/hip_runtime.h>

// Elementwise: out[i] = x[i] > 0 ? x[i]*x[i] : x[i]
// N = 2^26 fp32. Memory-bound: 536.9 MB total traffic.
// R1: grid-stride float4, 107.7us = 4.99 TB/s.
// R3: unroll x4 far-apart streams + nt(load+store) = 118us REGRESSION (confounded).
// R4: block-contiguous unroll x4, 16KiB tile/block = 96.6us = 5.56 TB/s.
// R5: unroll x8 = 97.5us, flat -> MLP saturated.
// R6: R4 + nt STORES = 81.1us = 6.62 TB/s (beats 6.29 copy ceiling).  <- best
// R7: R6 + nt LOADS (last isolated cache-policy lever; reads are zero-reuse too).

typedef float f4 __attribute__((ext_vector_type(4)));

__global__ __launch_bounds__(256) void sq_pos_kernel(const f4* __restrict__ x,
                                                     f4* __restrict__ out) {
    // Block tile: 4*256 f4 = 16 KiB. Thread t covers tile + t + k*256.
    const long long base = (long long)blockIdx.x * (4 * 256) + threadIdx.x;

    f4 v0 = __builtin_nontemporal_load(&x[base]);
    f4 v1 = __builtin_nontemporal_load(&x[base + 256]);
    f4 v2 = __builtin_nontemporal_load(&x[base + 512]);
    f4 v3 = __builtin_nontemporal_load(&x[base + 768]);

    auto f = [](f4 v) -> f4 {
        f4 r;
        r.x = v.x > 0.0f ? v.x * v.x : v.x;
        r.y = v.y > 0.0f ? v.y * v.y : v.y;
        r.z = v.z > 0.0f ? v.z * v.z : v.z;
        r.w = v.w > 0.0f ? v.w * v.w : v.w;
        return r;
    };

    __builtin_nontemporal_store(f(v0), &out[base]);
    __builtin_nontemporal_store(f(v1), &out[base + 256]);
    __builtin_nontemporal_store(f(v2), &out[base + 512]);
    __builtin_nontemporal_store(f(v3), &out[base + 768]);
}

// Generic fallback for sizes not divisible by 4096 floats (not hit for N=2^26).
__global__ void sq_pos_tail(const float* __restrict__ x, float* __restrict__ o,
                            long long start, long long n) {
    long long i = start + (long long)blockIdx.x * blockDim.x + threadIdx.x;
    if (i < n) { float v = x[i]; o[i] = v > 0.0f ? v * v : v; }
}

extern "C" void kernel_launch(void* const* d_in, const int* in_sizes, int n_in,
                              void* d_out, int out_size, void* d_ws, size_t ws_size,
                              hipStream_t stream) {
    const float* xf = (const float*)d_in[0];
    float* of = (float*)d_out;
    long long n = in_sizes[0];

    // Main kernel: each block handles 1024 f4 = 4096 floats.
    long long nblocks = n / 4096;
    if (nblocks > 0) {
        sq_pos_kernel<<<(int)nblocks, 256, 0, stream>>>((const f4*)xf, (f4*)of);
    }
    long long done = nblocks * 4096;
    if (done < n) {
        long long rem = n - done;
        int tgrid = (int)((rem + 255) / 256);
        sq_pos_tail<<<tgrid, 256, 0, stream>>>(xf, of, done, n);
    }
}

// Round 8
// 81.106 us; speedup vs baseline: 1.0987x; 1.0987x over previous
//
#include <hip/hip_runtime.h>

// Elementwise: out[i] = x[i] > 0 ? x[i]*x[i] : x[i]
// N = 2^26 fp32. Memory-bound: 536.9 MB total traffic.
// R1: grid-stride float4, 107.7us = 4.99 TB/s.
// R3: unroll x4 far-apart streams + nt(load+store) = 118us REGRESSION (confounded).
// R4: block-contiguous unroll x4, 16KiB tile/block = 96.6us = 5.56 TB/s.
// R5: unroll x8 = 97.5us, flat -> MLP saturated.
// R6: R4 + nt STORES = 81.1us = 6.62 TB/s (beats 6.29 copy ceiling).  <- BEST
// R7: R6 + nt LOADS = 89.1us REGRESSION (nt pays on write-allocate only;
//     nt loads forfeit read-side cache merging). REVERTED to R6.

typedef float f4 __attribute__((ext_vector_type(4)));

__global__ __launch_bounds__(256) void sq_pos_kernel(const f4* __restrict__ x,
                                                     f4* __restrict__ out) {
    // Block tile: 4*256 f4 = 16 KiB. Thread t covers tile + t + k*256.
    const long long base = (long long)blockIdx.x * (4 * 256) + threadIdx.x;

    f4 v0 = x[base];
    f4 v1 = x[base + 256];
    f4 v2 = x[base + 512];
    f4 v3 = x[base + 768];

    auto f = [](f4 v) -> f4 {
        f4 r;
        r.x = v.x > 0.0f ? v.x * v.x : v.x;
        r.y = v.y > 0.0f ? v.y * v.y : v.y;
        r.z = v.z > 0.0f ? v.z * v.z : v.z;
        r.w = v.w > 0.0f ? v.w * v.w : v.w;
        return r;
    };

    __builtin_nontemporal_store(f(v0), &out[base]);
    __builtin_nontemporal_store(f(v1), &out[base + 256]);
    __builtin_nontemporal_store(f(v2), &out[base + 512]);
    __builtin_nontemporal_store(f(v3), &out[base + 768]);
}

// Generic fallback for sizes not divisible by 4096 floats (not hit for N=2^26).
__global__ void sq_pos_tail(const float* __restrict__ x, float* __restrict__ o,
                            long long start, long long n) {
    long long i = start + (long long)blockIdx.x * blockDim.x + threadIdx.x;
    if (i < n) { float v = x[i]; o[i] = v > 0.0f ? v * v : v; }
}

extern "C" void kernel_launch(void* const* d_in, const int* in_sizes, int n_in,
                              void* d_out, int out_size, void* d_ws, size_t ws_size,
                              hipStream_t stream) {
    const float* xf = (const float*)d_in[0];
    float* of = (float*)d_out;
    long long n = in_sizes[0];

    // Main kernel: each block handles 1024 f4 = 4096 floats.
    long long nblocks = n / 4096;
    if (nblocks > 0) {
        sq_pos_kernel<<<(int)nblocks, 256, 0, stream>>>((const f4*)xf, (f4*)of);
    }
    long long done = nblocks * 4096;
    if (done < n) {
        long long rem = n - done;
        int tgrid = (int)((rem + 255) / 256);
        sq_pos_tail<<<tgrid, 256, 0, stream>>>(xf, of, done, n);
    }
}